// Round 1
// baseline (1134.913 us; speedup 1.0000x reference)
//
#include <hip/hip_runtime.h>
#include <math.h>

#define N_TOK 2048
#define BATCH 64
#define DIN   768
#define DMID  512
#define DOUT  128
#define TILE_N 32
#define KC    128   // k-chunk for GEMM1 staging of x

// Float atomic max via int/uint trick (order-preserving for IEEE-754).
__device__ __forceinline__ void atomicMaxFloat(float* addr, float val) {
    if (val >= 0.0f) atomicMax((int*)addr, __float_as_int(val));
    else             atomicMin((unsigned int*)addr, __float_as_uint(val));
}

__global__ void init_kernel(float* __restrict__ x1) {
    int i = blockIdx.x * blockDim.x + threadIdx.x;
    if (i < BATCH * DOUT) x1[i] = -INFINITY;
}

// One block = 32 rows of one sample b. Blocks not intersecting the segment exit.
__global__ __launch_bounds__(256) void fused_kernel(
    const float* __restrict__ x,   // (N, B, DIN)
    const float* __restrict__ W1,  // (DIN, DMID)
    const float* __restrict__ b1,  // (DMID)
    const float* __restrict__ W2,  // (DMID, DOUT)
    const float* __restrict__ b2,  // (DOUT)
    const int*   __restrict__ batch_list,
    float* __restrict__ x1)        // (B, DOUT), pre-set to -inf
{
    const int b    = blockIdx.y;
    const int row0 = blockIdx.x * TILE_N;

    const int start = (b == 0) ? 0 : batch_list[b - 1];
    const int len   = batch_list[b];
    const int end   = start + len;
    if (row0 >= end || row0 + TILE_N <= start) return;  // block-uniform exit

    __shared__ float xs[TILE_N][KC];     // 16 KB (x K-chunk; reused as reduce buf)
    __shared__ float hs[TILE_N][DMID];   // 64 KB (relu(xW1+b1) tile)

    const int tid = threadIdx.x;

    // ---------------- GEMM1: h[32][512] = relu(x_tile @ W1 + b1) ----------------
    // Thread tile 8x8: tr = tid/64 (rows tr*8..+7), tc = tid%64 (cols tc*8..+7).
    // Wave-uniform tr -> xs reads are broadcasts; W1 reads coalesced 32B/lane.
    const int tr = tid >> 6;
    const int tc = tid & 63;

    float acc[8][8];
    #pragma unroll
    for (int r = 0; r < 8; ++r)
        #pragma unroll
        for (int c = 0; c < 8; ++c) acc[r][c] = 0.0f;

    for (int kc = 0; kc < DIN; kc += KC) {
        __syncthreads();  // previous chunk's xs reads done
        // stage x chunk: 32 rows x 128 k = 1024 float4, 4 per thread, coalesced
        for (int i = tid; i < TILE_N * (KC / 4); i += 256) {
            const int r  = i / (KC / 4);
            const int kq = i % (KC / 4);
            const float4 v = *(const float4*)&x[((size_t)(row0 + r) * BATCH + b) * DIN + kc + kq * 4];
            *(float4*)&xs[r][kq * 4] = v;
        }
        __syncthreads();

        for (int k = 0; k < KC; ++k) {
            const float4 w0 = *(const float4*)&W1[(size_t)(kc + k) * DMID + tc * 8];
            const float4 w1 = *(const float4*)&W1[(size_t)(kc + k) * DMID + tc * 8 + 4];
            float wv[8] = {w0.x, w0.y, w0.z, w0.w, w1.x, w1.y, w1.z, w1.w};
            float xv[8];
            #pragma unroll
            for (int r = 0; r < 8; ++r) xv[r] = xs[tr * 8 + r][k];
            #pragma unroll
            for (int r = 0; r < 8; ++r)
                #pragma unroll
                for (int c = 0; c < 8; ++c)
                    acc[r][c] = fmaf(xv[r], wv[c], acc[r][c]);
        }
    }

    // bias + relu -> hs
    {
        const float4 bb0 = *(const float4*)&b1[tc * 8];
        const float4 bb1 = *(const float4*)&b1[tc * 8 + 4];
        const float bv[8] = {bb0.x, bb0.y, bb0.z, bb0.w, bb1.x, bb1.y, bb1.z, bb1.w};
        #pragma unroll
        for (int r = 0; r < 8; ++r)
            #pragma unroll
            for (int c = 0; c < 8; ++c)
                hs[tr * 8 + r][tc * 8 + c] = fmaxf(acc[r][c] + bv[c], 0.0f);
    }
    __syncthreads();

    // ---------------- GEMM2: x0[32][128] = h @ W2 + b2 ----------------
    // Thread tile 4x4: tr2 = tid/32 (rows tr2*4..+3), tc2 = tid%32 (cols tc2*4..+3).
    const int tr2 = tid >> 5;
    const int tc2 = tid & 31;

    float acc2[4][4];
    #pragma unroll
    for (int r = 0; r < 4; ++r)
        #pragma unroll
        for (int c = 0; c < 4; ++c) acc2[r][c] = 0.0f;

    for (int k = 0; k < DMID; ++k) {
        const float4 w = *(const float4*)&W2[(size_t)k * DOUT + tc2 * 4];
        float hv[4];
        #pragma unroll
        for (int r = 0; r < 4; ++r) hv[r] = hs[tr2 * 4 + r][k];
        #pragma unroll
        for (int r = 0; r < 4; ++r) {
            acc2[r][0] = fmaf(hv[r], w.x, acc2[r][0]);
            acc2[r][1] = fmaf(hv[r], w.y, acc2[r][1]);
            acc2[r][2] = fmaf(hv[r], w.z, acc2[r][2]);
            acc2[r][3] = fmaf(hv[r], w.w, acc2[r][3]);
        }
    }

    // bias + segment mask + per-thread row max (over this thread's 4 rows)
    const float4 bb = *(const float4*)&b2[tc2 * 4];
    const float bv2[4] = {bb.x, bb.y, bb.z, bb.w};
    float cmax[4] = {-INFINITY, -INFINITY, -INFINITY, -INFINITY};
    #pragma unroll
    for (int r = 0; r < 4; ++r) {
        const int row = row0 + tr2 * 4 + r;
        const bool in = (row >= start) && (row < end);
        #pragma unroll
        for (int c = 0; c < 4; ++c) {
            const float v = acc2[r][c] + bv2[c];
            if (in) cmax[c] = fmaxf(cmax[c], v);
        }
    }

    // block reduce over the 8 thread-row groups (reuse xs as [8][DOUT])
    float (*red)[DOUT] = (float(*)[DOUT])xs;
    #pragma unroll
    for (int c = 0; c < 4; ++c) red[tr2][tc2 * 4 + c] = cmax[c];
    __syncthreads();

    if (tid < DOUT) {
        float m = red[0][tid];
        #pragma unroll
        for (int r = 1; r < 8; ++r) m = fmaxf(m, red[r][tid]);
        atomicMaxFloat(&x1[b * DOUT + tid], m);
    }
}

// argmax(softmax(x1)) == argmax(x1); first-index tie semantics match strict >.
__global__ void argmax_kernel(const float* __restrict__ x1, float* __restrict__ probs) {
    int b = blockIdx.x * blockDim.x + threadIdx.x;
    if (b >= BATCH) return;
    const float* row = x1 + b * DOUT;
    float best = row[0];
    int bi = 0;
    for (int c = 1; c < DOUT; ++c) {
        float v = row[c];
        if (v > best) { best = v; bi = c; }
    }
    probs[b] = (float)bi;
}

extern "C" void kernel_launch(void* const* d_in, const int* in_sizes, int n_in,
                              void* d_out, int out_size, void* d_ws, size_t ws_size,
                              hipStream_t stream) {
    const float* x          = (const float*)d_in[0];
    const float* W1         = (const float*)d_in[1];
    const float* b1         = (const float*)d_in[2];
    const float* W2         = (const float*)d_in[3];
    const float* b2         = (const float*)d_in[4];
    const int*   batch_list = (const int*)d_in[5];
    // d_in[6] = batch_size scalar (unused; compile-time BATCH)

    float* x1    = (float*)d_out;          // 64*128
    float* probs = x1 + BATCH * DOUT;      // 64

    init_kernel<<<(BATCH * DOUT + 255) / 256, 256, 0, stream>>>(x1);

    dim3 grid(N_TOK / TILE_N, BATCH);
    fused_kernel<<<grid, 256, 0, stream>>>(x, W1, b1, W2, b2, batch_list, x1);

    argmax_kernel<<<1, 64, 0, stream>>>(x1, probs);
}